// Round 6
// baseline (307.862 us; speedup 1.0000x reference)
//
#include <hip/hip_runtime.h>
#include <hip/hip_bf16.h>

#define T_SEQ 2048
#define BATCH 2
#define CDIM  2048
#define NH    16
#define NKV   4
#define DH    128

typedef __attribute__((ext_vector_type(8))) short bfrag;   // 8 bf16 (4 VGPRs)
typedef __attribute__((ext_vector_type(4))) short bhalf;   // 4 bf16 (2 VGPRs)
typedef __attribute__((ext_vector_type(4))) float ffrag;   // 4 f32 acc
typedef __hip_bfloat16 bf16;

__device__ __forceinline__ void gll16(const bf16* __restrict__ g, bf16* lds) {
    __builtin_amdgcn_global_load_lds((const __attribute__((address_space(1))) void*)g,
                                     (__attribute__((address_space(3))) void*)lds, 16, 0, 0);
}

__device__ __forceinline__ unsigned cvt_pk_bf16(float lo, float hi) {
    unsigned r;
    asm("v_cvt_pk_bf16_f32 %0, %1, %2" : "=v"(r) : "v"(lo), "v"(hi));
    return r;   // low16 = bf16(lo), high16 = bf16(hi)
}

// ---------------- merged fp32 -> bf16 cast of all 4 inputs ----------------
struct bf16x4 { bf16 a, b, c, d; };
#define N4_X   (BATCH * T_SEQ * CDIM / 4)
#define N4_WQ  (CDIM * CDIM / 4)
#define N4_WKV (2 * NKV * DH * CDIM / 4)
#define N4_WP  (CDIM * CDIM / 4)
__global__ __launch_bounds__(256) void cast_all(
    const float* __restrict__ x, const float* __restrict__ wq,
    const float* __restrict__ wkv, const float* __restrict__ wp,
    bf16* __restrict__ xb, bf16* __restrict__ wqb, bf16* __restrict__ wkvb, bf16* __restrict__ wpb)
{
    int j = blockIdx.x * 256 + threadIdx.x;
    const float* s; bf16* d;
    if (j < N4_X) { s = x; d = xb; }
    else {
        j -= N4_X;
        if (j < N4_WQ) { s = wq; d = wqb; }
        else {
            j -= N4_WQ;
            if (j < N4_WKV) { s = wkv; d = wkvb; }
            else { j -= N4_WKV; if (j >= N4_WP) return; s = wp; d = wpb; }
        }
    }
    float4 f = ((const float4*)s)[j];
    bf16x4 o{__float2bfloat16(f.x), __float2bfloat16(f.y),
             __float2bfloat16(f.z), __float2bfloat16(f.w)};
    ((bf16x4*)d)[j] = o;
}

// ---------------- GEMM: m97/TLP structure + zero-conflict LDS geometry ----------------
// 128x128 tile, 4 waves (2M x 2N), BK=32, single LDS buffer, 2 __syncthreads per tile,
// multi-block TLP hides the barrier drain. LDS: logical [128 rows][32 k] packed as
// phys [64 rows][64 elems]; 16B slot ^= (prow & 7), applied to the global SOURCE for
// staging (global_load_lds writes linearly) and to the ds_read address.
// Measured SQ_LDS_BANK_CONFLICT == 0 with this geometry.
// Shared arrays are hoisted to kernel scope (a per-instantiation __shared__ inside the
// template doubled gemm_qkv's LDS to 32 KB -> measured; now 17 KB once).
//
// MODE: 0 = q with fused RMSNorm+rotary; 1 = k with fused RMSNorm+rotary;
//       3 = v (transposed write, no norm); 2 = proj (fp32 out).
// Fused normrope geometry: lane's d = g*32 + wn*16 + lr, so rotary pair (d, d+64) is
// lane-local (g <-> g+2), freq != 0 only for g==0 (d<32), and theta = h*freq with h
// block-constant (reference rotates by HEAD index: _apply_rotary uses shape[-3]).
// RMS sum: 16-lane shfl_xor reduce (this wn-half) + 1KB LDS exchange across wn waves.
template<int MODE>
__device__ __forceinline__ void gemm_body(
    const bf16* __restrict__ A, const bf16* __restrict__ W, int m0, int n0,
    bf16* __restrict__ out0, bf16* __restrict__ out1, float* __restrict__ outf,
    bf16* __restrict__ sA, bf16* __restrict__ sB, float (* __restrict__ hb)[128])
{
    const int lane = threadIdx.x & 63;
    const int w    = threadIdx.x >> 6;           // 0..3
    const int wm   = w >> 1, wn = w & 1;
    const int lr   = lane & 15, quad = lane >> 4;

    const int pr8  = lane >> 3;                  // phys row-in-8
    const int ls   = (lane & 7) ^ pr8;           // logical slot after inverse swizzle
    const int rloc = 2 * (w * 8 + pr8) + (ls >> 2);  // logical row within 64-row block-load
    const int k0s  = (ls & 3) * 8;               // k sub-offset 0..24

    const bf16* Aj0 = A + (size_t)(m0 +      rloc) * CDIM + k0s;
    const bf16* Aj1 = A + (size_t)(m0 + 64 + rloc) * CDIM + k0s;
    const bf16* Bj0 = W + (size_t)(n0 +      rloc) * CDIM + k0s;
    const bf16* Bj1 = W + (size_t)(n0 + 64 + rloc) * CDIM + k0s;
    bf16* dA0 = sA +        w * 512;             // wave-uniform LDS dest (elems)
    bf16* dA1 = sA + 2048 + w * 512;
    bf16* dB0 = sB +        w * 512;
    bf16* dB1 = sB + 2048 + w * 512;

    const int soff = ((((lr & 1) << 2) | quad) ^ ((lr >> 1) & 7)) << 3;

    ffrag acc[4][4] = {};
    for (int kk = 0; kk < CDIM; kk += 32) {
        __syncthreads();                         // all waves done reading previous tile
        gll16(Aj0 + kk, dA0);
        gll16(Aj1 + kk, dA1);
        gll16(Bj0 + kk, dB0);
        gll16(Bj1 + kk, dB1);
        __syncthreads();                         // vmcnt(0) drain + barrier: staged data visible

        bfrag af[4], bg[4];
        #pragma unroll
        for (int f = 0; f < 4; ++f)
            af[f] = *(const bfrag*)&sA[((f * 16 + wm * 8 + (lr >> 1)) << 6) + soff];
        #pragma unroll
        for (int g = 0; g < 4; ++g)
            bg[g] = *(const bfrag*)&sB[((g * 16 + wn * 8 + (lr >> 1)) << 6) + soff];
        #pragma unroll
        for (int f = 0; f < 4; ++f)
            #pragma unroll
            for (int g = 0; g < 4; ++g)
                acc[f][g] = __builtin_amdgcn_mfma_f32_16x16x32_bf16(af[f], bg[g], acc[f][g], 0, 0, 0);
    }

    if constexpr (MODE == 0 || MODE == 1) {
        // ---- fused RMSNorm + rotary (by head index, matching the reference) ----
        float ssh[4][4];
        #pragma unroll
        for (int f = 0; f < 4; ++f)
            #pragma unroll
            for (int i = 0; i < 4; ++i) {
                float ss = acc[f][0][i] * acc[f][0][i] + acc[f][1][i] * acc[f][1][i]
                         + acc[f][2][i] * acc[f][2][i] + acc[f][3][i] * acc[f][3][i];
                #pragma unroll
                for (int off = 1; off < 16; off <<= 1) ss += __shfl_xor(ss, off);
                ssh[f][i] = ss;                  // this wn-half's 64-d sum for row (f,i)
            }
        if (lr == 0) {
            #pragma unroll
            for (int f = 0; f < 4; ++f)
                #pragma unroll
                for (int i = 0; i < 4; ++i)
                    hb[wn][f * 32 + wm * 16 + quad * 4 + i] = ssh[f][i];
        }
        __syncthreads();
        const int h_angle = n0 >> 7;             // head index (block-constant)
        const float freq = exp2f(-10.0f * (float)(wn * 16 + lr) * (1.0f / 31.0f));
        float sn, cs;
        __sincosf((float)h_angle * freq, &sn, &cs);
        #pragma unroll
        for (int f = 0; f < 4; ++f)
            #pragma unroll
            for (int i = 0; i < 4; ++i) {
                float ss = ssh[f][i] + hb[wn ^ 1][f * 32 + wm * 16 + quad * 4 + i];
                float r = rsqrtf(ss * (1.0f / 128.0f) + 1.1920929e-07f);
                float x0 = acc[f][0][i] * r, x1 = acc[f][1][i] * r;
                float x2 = acc[f][2][i] * r, x3 = acc[f][3][i] * r;
                acc[f][0][i] =  x0 * cs + x2 * sn;   // d < 32: rotate with pair d+64
                acc[f][2][i] = -x0 * sn + x2 * cs;
                acc[f][1][i] = x1;                   // 32 <= d < 64: freq = 0
                acc[f][3][i] = x3;
            }
    }

    #pragma unroll
    for (int f = 0; f < 4; ++f) {
        #pragma unroll
        for (int g = 0; g < 4; ++g) {
            #pragma unroll
            for (int i = 0; i < 4; ++i) {
                const int m = m0 + f * 32 + wm * 16 + quad * 4 + i;
                const int n = n0 + g * 32 + wn * 16 + lr;
                const float v = acc[f][g][i];
                if constexpr (MODE == 0) {
                    int b = m >> 11, t = m & (T_SEQ - 1);
                    int h = n >> 7, d = n & (DH - 1);
                    out0[(((size_t)(b * NH + h) * T_SEQ + t) << 7) + d] = __float2bfloat16(v);
                } else if constexpr (MODE == 1) {
                    int b = m >> 11, t = m & (T_SEQ - 1);
                    int h = n >> 7, d = n & (DH - 1);
                    out0[(((size_t)(b * NKV + h) * T_SEQ + t) << 7) + d] = __float2bfloat16(v);
                } else if constexpr (MODE == 3) {
                    int b = m >> 11, t = m & (T_SEQ - 1);
                    int n2 = n - NKV * DH;
                    int h = n2 >> 7, d = n2 & (DH - 1);
                    out1[(((size_t)(b * NKV + h) * DH + d) << 11) + t] = __float2bfloat16(v);
                } else {
                    outf[(size_t)m * CDIM + n] = v;
                }
            }
        }
    }
}

__global__ __launch_bounds__(256) void gemm_qkv(
    const bf16* __restrict__ A, const bf16* __restrict__ Wq, const bf16* __restrict__ Wkv,
    bf16* __restrict__ q, bf16* __restrict__ k, bf16* __restrict__ vt)
{
    __shared__ __align__(16) bf16 sA[64 * 64];   // 8 KiB (shared across instantiations)
    __shared__ __align__(16) bf16 sB[64 * 64];   // 8 KiB
    __shared__ float hb[2][128];                 // 1 KiB norm-exchange
    const int y = blockIdx.y;
    if (y < 16)
        gemm_body<0>(A, Wq,  blockIdx.x * 128, y * 128,        q, nullptr, nullptr, sA, sB, hb);
    else if (y < 20)
        gemm_body<1>(A, Wkv, blockIdx.x * 128, (y - 16) * 128, k, nullptr, nullptr, sA, sB, hb);
    else
        gemm_body<3>(A, Wkv, blockIdx.x * 128, (y - 16) * 128, nullptr, vt, nullptr, sA, sB, hb);
}

__global__ __launch_bounds__(256) void gemm_proj(
    const bf16* __restrict__ A, const bf16* __restrict__ W, float* __restrict__ outf)
{
    __shared__ __align__(16) bf16 sA[64 * 64];
    __shared__ __align__(16) bf16 sB[64 * 64];
    gemm_body<2>(A, W, blockIdx.x * 128, blockIdx.y * 128, nullptr, nullptr, outf,
                 sA, sB, nullptr);
    if (blockIdx.x == 0 && blockIdx.y == 0 && threadIdx.x == 0)
        outf[(size_t)BATCH * T_SEQ * CDIM] = 0.0f;   // reference's second output: 0.0
}

// ---------------- Flash attention v7: double-buffered K/V, 1 barrier per chunk ----------------
// Static-max softmax (RMS-normed q,k => |score*scale| <= 11.32; exp(s-16) exact).
// Block = 512 thr: group g = waves 0-3 / 4-7; both groups cover the same 128 q-rows
// (wave wl -> rows qb*128 + wl*32, two 16-row tiles) but disjoint 32-key chunks
// (abs chunk 2c+g). Partial (O, l) add linearly (static max) -> fp32 LDS merge.
// Pass pairing (p, 15-p) => uniform 34 group-chunks/block.
// One __syncthreads per chunk: iteration c writes prefetched chunk c+1 into buf^1,
// issues the global prefetch of c+2, computes chunk c from buf, then barriers.
// QK^T swapped (mfma(kf,qf)): lane holds S[k][q=lr]; PV A-fragment built in-register
// with v_cvt_pk_bf16_f32 (no LDS round-trip for P); V k-order permuted at load.
__global__ __launch_bounds__(512, 2) void attn_k(const bf16* __restrict__ Q, const bf16* __restrict__ K,
                                                 const bf16* __restrict__ VT, bf16* __restrict__ Y)
{
    const int lane = threadIdx.x & 63;
    const int w = threadIdx.x >> 6;          // 0..7
    const int g = w >> 2, wl = w & 3;
    const int p = blockIdx.x, h = blockIdx.y, b = blockIdx.z;
    const int lr = lane & 15, quad = lane >> 4, lk = quad * 8;
    const bf16* Qb = Q  + (size_t)(b * NH  + h)        * T_SEQ * DH;
    const bf16* Kb = K  + (size_t)(b * NKV + (h >> 2)) * T_SEQ * DH;
    const bf16* Vb = VT + (size_t)(b * NKV + (h >> 2)) * DH * T_SEQ;

    __shared__ __align__(16) union ShmU {
        struct { bf16 SK[2][2][32 * 128]; bf16 SV[2][2][128 * 32]; } s;   // 64 KiB (dbuf)
        ffrag MRG[9 * 4 * 64];               // 36864 B merge area (aliases SK/SV)
    } shm;

    // staging coords: K chunk 32(keys)x128, V chunk 128(d)x32(keys), per group
    const int k_r0 = wl * 8 + (lane >> 4);   // + j*4
    const int k_ch = lane & 15;
    const int v_r0 = wl * 32 + (lane >> 2);  // + j*16
    const int v_ch = lane & 3;
    const int vsw = (lr + (lr >> 2)) & 3;    // SV read swizzle (row = dt*16+lr)
    const float scale = 0.08838834764831845f;            // 1/sqrt(128)

    // k-permuted V load: slot v_ch holds k = {4*v_ch..+3, 16+4*v_ch..+3}
    auto load_v_perm = [&](const bf16* rp) {
        union { bhalf h[2]; bfrag f; } u;
        u.h[0] = *(const bhalf*)(rp + v_ch * 4);
        u.h[1] = *(const bhalf*)(rp + 16 + v_ch * 4);
        return u.f;
    };

    for (int pass = 0; pass < 2; ++pass) {
        const int qb = pass ? (15 - p) : p;
        const int nc = 2 * (qb + 1);         // 32-key chunks for THIS group
        const int q0 = qb * 128 + wl * 32;

        bfrag qf[2][4];
        #pragma unroll
        for (int t = 0; t < 2; ++t)
            #pragma unroll
            for (int dc = 0; dc < 4; ++dc)
                qf[t][dc] = *(const bfrag*)(Qb + (size_t)(q0 + t * 16 + lr) * DH + dc * 32 + lk);

        float lp[2] = {};
        ffrag o[2][8] = {};

        bfrag kr[2], vr[2];
        // prologue: load chunk 0, write it to buf 0, then prefetch chunk 1
        {
            const int b0 = g * 32;
            #pragma unroll
            for (int j = 0; j < 2; ++j) {
                kr[j] = *(const bfrag*)(Kb + (size_t)(b0 + k_r0 + j * 4) * DH + k_ch * 8);
                vr[j] = load_v_perm(Vb + (size_t)(v_r0 + j * 16) * T_SEQ + b0);
            }
            #pragma unroll
            for (int j = 0; j < 2; ++j) {
                int krow = k_r0 + j * 4;
                *(bfrag*)&shm.s.SK[g][0][krow * 128 + ((k_ch ^ (krow & 15))) * 8] = kr[j];
                int vrow = v_r0 + j * 16;
                *(bfrag*)&shm.s.SV[g][0][vrow * 32 + ((v_ch ^ ((vrow + (vrow >> 2)) & 3))) * 8] = vr[j];
            }
            if (nc > 1) {
                const int nb = 64 + g * 32;
                #pragma unroll
                for (int j = 0; j < 2; ++j) {
                    kr[j] = *(const bfrag*)(Kb + (size_t)(nb + k_r0 + j * 4) * DH + k_ch * 8);
                    vr[j] = load_v_perm(Vb + (size_t)(v_r0 + j * 16) * T_SEQ + nb);
                }
            }
        }
        __syncthreads();                     // buf 0 visible (also isolates prior MRG use)

        for (int c = 0; c < nc; ++c) {
            const int cur = c & 1, nxt = cur ^ 1;
            const int base = c * 64 + g * 32;
            const bf16* SKc = shm.s.SK[g][cur];
            const bf16* SVc = shm.s.SV[g][cur];

            if (c + 1 < nc) {                // write prefetched chunk c+1 into buf^1
                #pragma unroll
                for (int j = 0; j < 2; ++j) {
                    int krow = k_r0 + j * 4;
                    *(bfrag*)&shm.s.SK[g][nxt][krow * 128 + ((k_ch ^ (krow & 15))) * 8] = kr[j];
                    int vrow = v_r0 + j * 16;
                    *(bfrag*)&shm.s.SV[g][nxt][vrow * 32 + ((v_ch ^ ((vrow + (vrow >> 2)) & 3))) * 8] = vr[j];
                }
                if (c + 2 < nc) {            // prefetch chunk c+2 (hides under compute)
                    const int nb = (c + 2) * 64 + g * 32;
                    #pragma unroll
                    for (int j = 0; j < 2; ++j) {
                        kr[j] = *(const bfrag*)(Kb + (size_t)(nb + k_r0 + j * 4) * DH + k_ch * 8);
                        vr[j] = load_v_perm(Vb + (size_t)(v_r0 + j * 16) * T_SEQ + nb);
                    }
                }
            }

            // QK^T (swapped): s2[t][kt][i] = S[k = base + kt*16 + quad*4 + i][q = q0 + t*16 + lr]
            ffrag s2[2][2] = {};
            #pragma unroll
            for (int kt = 0; kt < 2; ++kt)
                #pragma unroll
                for (int dc = 0; dc < 4; ++dc) {
                    bfrag kf = *(const bfrag*)&SKc[(kt * 16 + lr) * 128 + (((dc << 2) | quad) ^ lr) * 8];
                    s2[0][kt] = __builtin_amdgcn_mfma_f32_16x16x32_bf16(kf, qf[0][dc], s2[0][kt], 0, 0, 0);
                    s2[1][kt] = __builtin_amdgcn_mfma_f32_16x16x32_bf16(kf, qf[1][dc], s2[1][kt], 0, 0, 0);
                }

            // softmax numerator (static max); P built in-register (no LDS round-trip)
            const bool maskc = (c >= 2 * qb);
            bfrag pf[2];
            #pragma unroll
            for (int t = 0; t < 2; ++t) {
                const int qa = q0 + t * 16 + lr;
                float ev[2][4];
                #pragma unroll
                for (int kt = 0; kt < 2; ++kt)
                    #pragma unroll
                    for (int i = 0; i < 4; ++i) {
                        const int ka = base + kt * 16 + quad * 4 + i;
                        float e = (!maskc || ka <= qa) ? __expf(fmaf(s2[t][kt][i], scale, -16.0f)) : 0.0f;
                        lp[t] += e;
                        ev[kt][i] = e;
                    }
                union { unsigned u[4]; bfrag f; } pu;
                pu.u[0] = cvt_pk_bf16(ev[0][0], ev[0][1]);
                pu.u[1] = cvt_pk_bf16(ev[0][2], ev[0][3]);
                pu.u[2] = cvt_pk_bf16(ev[1][0], ev[1][1]);
                pu.u[3] = cvt_pk_bf16(ev[1][2], ev[1][3]);
                pf[t] = pu.f;
            }

            // P.V: pf is the A-fragment directly (k-order matches V's slot permutation)
            #pragma unroll
            for (int dt = 0; dt < 8; ++dt) {
                bfrag vf = *(const bfrag*)&SVc[(dt * 16 + lr) * 32 + ((quad ^ vsw)) * 8];
                o[0][dt] = __builtin_amdgcn_mfma_f32_16x16x32_bf16(pf[0], vf, o[0][dt], 0, 0, 0);
                o[1][dt] = __builtin_amdgcn_mfma_f32_16x16x32_bf16(pf[1], vf, o[1][dt], 0, 0, 0);
            }

            __syncthreads();                 // single barrier: cur fully read, nxt fully written
        }

        // merge groups (fp32, two rounds to fit LDS) + epilogue by group 0
        __syncthreads();
        #pragma unroll
        for (int t = 0; t < 2; ++t) {
            if (g == 1) {
                #pragma unroll
                for (int d = 0; d < 8; ++d) shm.MRG[(d * 4 + wl) * 64 + lane] = o[t][d];
                ffrag l4 = {lp[t], 0.0f, 0.0f, 0.0f};
                shm.MRG[(8 * 4 + wl) * 64 + lane] = l4;
            }
            __syncthreads();
            if (g == 0) {
                #pragma unroll
                for (int d = 0; d < 8; ++d) o[t][d] += shm.MRG[(d * 4 + wl) * 64 + lane];
                float lsum = lp[t] + shm.MRG[(8 * 4 + wl) * 64 + lane][0];
                lsum += __shfl_xor(lsum, 16);
                lsum += __shfl_xor(lsum, 32);         // total l for q = lr, all quads
                float inv[4];
                #pragma unroll
                for (int i = 0; i < 4; ++i)
                    inv[i] = 1.0f / __shfl(lsum, quad * 4 + i);   // l for q = quad*4+i
                #pragma unroll
                for (int dt = 0; dt < 8; ++dt)
                    #pragma unroll
                    for (int i = 0; i < 4; ++i) {
                        int row = q0 + t * 16 + quad * 4 + i;
                        Y[((size_t)(b * T_SEQ) + row) * CDIM + h * DH + dt * 16 + lr] =
                            __float2bfloat16(o[t][dt][i] * inv[i]);
                    }
            }
            __syncthreads();                 // protect MRG before next round / next pass
        }
    }
}

extern "C" void kernel_launch(void* const* d_in, const int* in_sizes, int n_in,
                              void* d_out, int out_size, void* d_ws, size_t ws_size,
                              hipStream_t stream) {
    const float* x     = (const float*)d_in[0];
    const float* Wq    = (const float*)d_in[1];
    const float* Wkv   = (const float*)d_in[2];
    const float* Wproj = (const float*)d_in[3];
    float* out = (float*)d_out;

    char* ws = (char*)d_ws;
    size_t off = 0;
    auto alloc = [&](size_t bytes) { void* p = ws + off; off += (bytes + 255) & ~255ULL; return p; };
    bf16* xb   = (bf16*)alloc((size_t)BATCH * T_SEQ * CDIM * 2);
    bf16* wqb  = (bf16*)alloc((size_t)CDIM * CDIM * 2);
    bf16* wkvb = (bf16*)alloc((size_t)2 * NKV * DH * CDIM * 2);
    bf16* wpb  = (bf16*)alloc((size_t)CDIM * CDIM * 2);
    bf16* qb   = (bf16*)alloc((size_t)BATCH * NH * T_SEQ * DH * 2);
    bf16* kb   = (bf16*)alloc((size_t)BATCH * NKV * T_SEQ * DH * 2);
    bf16* vtb  = (bf16*)alloc((size_t)BATCH * NKV * DH * T_SEQ * 2);
    bf16* y1   = (bf16*)alloc((size_t)BATCH * T_SEQ * CDIM * 2);

    const int total4 = N4_X + N4_WQ + N4_WKV + N4_WP;
    cast_all<<<(total4 + 255) / 256, 256, 0, stream>>>(x, Wq, Wkv, Wproj, xb, wqb, wkvb, wpb);

    gemm_qkv<<<dim3(32, 24), 256, 0, stream>>>(xb, wqb, wkvb, qb, kb, vtb);
    attn_k<<<dim3(8, NH, BATCH), 512, 0, stream>>>(qb, kb, vtb, y1);
    gemm_proj<<<dim3(32, 16), 256, 0, stream>>>(y1, wpb, out);
}

// Round 7
// 296.736 us; speedup vs baseline: 1.0375x; 1.0375x over previous
//
#include <hip/hip_runtime.h>
#include <hip/hip_bf16.h>

#define T_SEQ 2048
#define BATCH 2
#define CDIM  2048
#define NH    16
#define NKV   4
#define DH    128

typedef __attribute__((ext_vector_type(8))) short bfrag;   // 8 bf16 (4 VGPRs)
typedef __attribute__((ext_vector_type(4))) short bhalf;   // 4 bf16 (2 VGPRs)
typedef __attribute__((ext_vector_type(4))) float ffrag;   // 4 f32 acc
typedef __hip_bfloat16 bf16;

__device__ __forceinline__ void gll16(const bf16* __restrict__ g, bf16* lds) {
    __builtin_amdgcn_global_load_lds((const __attribute__((address_space(1))) void*)g,
                                     (__attribute__((address_space(3))) void*)lds, 16, 0, 0);
}

__device__ __forceinline__ unsigned cvt_pk_bf16(float lo, float hi) {
    unsigned r;
    asm("v_cvt_pk_bf16_f32 %0, %1, %2" : "=v"(r) : "v"(lo), "v"(hi));
    return r;   // low16 = bf16(lo), high16 = bf16(hi)
}

// ---------------- merged fp32 -> bf16 cast of all 4 inputs ----------------
struct bf16x4 { bf16 a, b, c, d; };
#define N4_X   (BATCH * T_SEQ * CDIM / 4)
#define N4_WQ  (CDIM * CDIM / 4)
#define N4_WKV (2 * NKV * DH * CDIM / 4)
#define N4_WP  (CDIM * CDIM / 4)
__global__ __launch_bounds__(256) void cast_all(
    const float* __restrict__ x, const float* __restrict__ wq,
    const float* __restrict__ wkv, const float* __restrict__ wp,
    bf16* __restrict__ xb, bf16* __restrict__ wqb, bf16* __restrict__ wkvb, bf16* __restrict__ wpb)
{
    int j = blockIdx.x * 256 + threadIdx.x;
    const float* s; bf16* d;
    if (j < N4_X) { s = x; d = xb; }
    else {
        j -= N4_X;
        if (j < N4_WQ) { s = wq; d = wqb; }
        else {
            j -= N4_WQ;
            if (j < N4_WKV) { s = wkv; d = wkvb; }
            else { j -= N4_WKV; if (j >= N4_WP) return; s = wp; d = wpb; }
        }
    }
    float4 f = ((const float4*)s)[j];
    bf16x4 o{__float2bfloat16(f.x), __float2bfloat16(f.y),
             __float2bfloat16(f.z), __float2bfloat16(f.w)};
    ((bf16x4*)d)[j] = o;
}

// ---------------- GEMM: m97/TLP structure + zero-conflict LDS geometry ----------------
// Tile 128 x BN, 4 waves (2M x 2N for BN=128; 2M x 2N over 64 for BN=64), BK=32,
// single LDS buffer, 2 __syncthreads per tile, multi-block TLP hides the barrier drain.
// LDS: logical [rows][32 k] packed as phys [rows/2][64 elems]; 16B slot ^= (prow & 7),
// applied to the global SOURCE for staging (global_load_lds writes linearly) and to
// the ds_read address. Measured SQ_LDS_BANK_CONFLICT == 0 with this geometry.
// Shared arrays hoisted to kernel scope (per-instantiation __shared__ doubled LDS).
// BN=64 (proj): half B-panel per block -> grid 1024 = 4 blocks/CU (TLP) at the cost
// of 1.5x staging issue per FLOP; acc halves to 4x2 frags.
template<int MODE, int BN>
__device__ __forceinline__ void gemm_body(
    const bf16* __restrict__ A, const bf16* __restrict__ W, int m0, int n0,
    bf16* __restrict__ out0, bf16* __restrict__ out1, float* __restrict__ outf,
    bf16* __restrict__ sA, bf16* __restrict__ sB)
{
    constexpr int NG = BN / 32;                  // n-frags per wave (4 or 2)

    const int lane = threadIdx.x & 63;
    const int w    = threadIdx.x >> 6;           // 0..3
    const int wm   = w >> 1, wn = w & 1;
    const int lr   = lane & 15, quad = lane >> 4;

    const int pr8  = lane >> 3;                  // phys row-in-8
    const int ls   = (lane & 7) ^ pr8;           // logical slot after inverse swizzle
    const int rloc = 2 * (w * 8 + pr8) + (ls >> 2);  // logical row within 64-row block-load
    const int k0s  = (ls & 3) * 8;               // k sub-offset 0..24

    const bf16* Aj0 = A + (size_t)(m0 +      rloc) * CDIM + k0s;
    const bf16* Aj1 = A + (size_t)(m0 + 64 + rloc) * CDIM + k0s;
    const bf16* Bj0 = W + (size_t)(n0 +      rloc) * CDIM + k0s;
    const bf16* Bj1 = W + (size_t)(n0 + 64 + rloc) * CDIM + k0s;   // unused if BN==64
    bf16* dA0 = sA +        w * 512;             // wave-uniform LDS dest (elems)
    bf16* dA1 = sA + 2048 + w * 512;
    bf16* dB0 = sB +        w * 512;
    bf16* dB1 = sB + 2048 + w * 512;

    const int soff = ((((lr & 1) << 2) | quad) ^ ((lr >> 1) & 7)) << 3;

    ffrag acc[4][NG] = {};
    for (int kk = 0; kk < CDIM; kk += 32) {
        __syncthreads();                         // all waves done reading previous tile
        gll16(Aj0 + kk, dA0);
        gll16(Aj1 + kk, dA1);
        gll16(Bj0 + kk, dB0);
        if constexpr (BN == 128) gll16(Bj1 + kk, dB1);
        __syncthreads();                         // vmcnt(0) drain + barrier: staged data visible

        bfrag af[4], bg[NG];
        #pragma unroll
        for (int f = 0; f < 4; ++f)
            af[f] = *(const bfrag*)&sA[((f * 16 + wm * 8 + (lr >> 1)) << 6) + soff];
        #pragma unroll
        for (int g = 0; g < NG; ++g)
            bg[g] = *(const bfrag*)&sB[((g * 16 + wn * 8 + (lr >> 1)) << 6) + soff];
        #pragma unroll
        for (int f = 0; f < 4; ++f)
            #pragma unroll
            for (int g = 0; g < NG; ++g)
                acc[f][g] = __builtin_amdgcn_mfma_f32_16x16x32_bf16(af[f], bg[g], acc[f][g], 0, 0, 0);
    }

    #pragma unroll
    for (int f = 0; f < 4; ++f) {
        #pragma unroll
        for (int g = 0; g < NG; ++g) {
            #pragma unroll
            for (int i = 0; i < 4; ++i) {
                const int m = m0 + f * 32 + wm * 16 + quad * 4 + i;
                const int n = n0 + g * 32 + wn * 16 + lr;
                const float v = acc[f][g][i];
                if constexpr (MODE == 0) {
                    int b = m >> 11, t = m & (T_SEQ - 1);
                    int h = n >> 7, d = n & (DH - 1);
                    out0[(((size_t)(b * NH + h) * T_SEQ + t) << 7) + d] = __float2bfloat16(v);
                } else if constexpr (MODE == 1) {
                    int b = m >> 11, t = m & (T_SEQ - 1);
                    if (n < NKV * DH) {
                        int h = n >> 7, d = n & (DH - 1);
                        out0[(((size_t)(b * NKV + h) * T_SEQ + t) << 7) + d] = __float2bfloat16(v);
                    } else {
                        int n2 = n - NKV * DH;
                        int h = n2 >> 7, d = n2 & (DH - 1);
                        out1[(((size_t)(b * NKV + h) * DH + d) << 11) + t] = __float2bfloat16(v);
                    }
                } else {
                    outf[(size_t)m * CDIM + n] = v;
                }
            }
        }
    }
}

__global__ __launch_bounds__(256) void gemm_qkv(
    const bf16* __restrict__ A, const bf16* __restrict__ Wq, const bf16* __restrict__ Wkv,
    bf16* __restrict__ q, bf16* __restrict__ k, bf16* __restrict__ vt)
{
    __shared__ __align__(16) bf16 sA[64 * 64];   // 8 KiB (shared across instantiations)
    __shared__ __align__(16) bf16 sB[64 * 64];   // 8 KiB
    if (blockIdx.y < 16)
        gemm_body<0, 128>(A, Wq, blockIdx.x * 128, blockIdx.y * 128, q, nullptr, nullptr, sA, sB);
    else
        gemm_body<1, 128>(A, Wkv, blockIdx.x * 128, (blockIdx.y - 16) * 128, k, vt, nullptr, sA, sB);
}

__global__ __launch_bounds__(256) void gemm_proj(
    const bf16* __restrict__ A, const bf16* __restrict__ W, float* __restrict__ outf)
{
    __shared__ __align__(16) bf16 sA[64 * 64];   // 8 KiB
    __shared__ __align__(16) bf16 sB[32 * 64];   // 4 KiB (BN=64)
    gemm_body<2, 64>(A, W, blockIdx.x * 128, blockIdx.y * 64, nullptr, nullptr, outf, sA, sB);
    if (blockIdx.x == 0 && blockIdx.y == 0 && threadIdx.x == 0)
        outf[(size_t)BATCH * T_SEQ * CDIM] = 0.0f;   // reference's second output: 0.0
}

// ---------------- RMSNorm + rotary, q and k fused in one launch ----------------
#define QROWS (BATCH * NH * T_SEQ)
#define KROWS (BATCH * NKV * T_SEQ)
__global__ __launch_bounds__(256) void normrope_k(bf16* __restrict__ qb, bf16* __restrict__ kb) {
    int row = blockIdx.x * 4 + (threadIdx.x >> 6);
    bf16* bufb; int nheads;
    if (row < QROWS) { bufb = qb; nheads = NH; }
    else { row -= QROWS; bufb = kb; nheads = NKV; }
    const int h = (row >> 11) % nheads;            // T = 2^11; angle uses HEAD idx (per ref)
    bf16* p = bufb + (size_t)row * DH;
    const int d = threadIdx.x & 63;
    float x1 = __bfloat162float(p[d]);
    float x2 = __bfloat162float(p[d + 64]);
    float ss = x1 * x1 + x2 * x2;
    #pragma unroll
    for (int off = 32; off; off >>= 1) ss += __shfl_xor(ss, off);
    float r = rsqrtf(ss * (1.0f / 128.0f) + 1.1920929e-07f);
    x1 *= r; x2 *= r;
    float freq = (d < 32) ? exp2f(-10.0f * (float)d * (1.0f / 31.0f)) : 0.0f;
    float th = (float)h * freq;
    float c, s;
    __sincosf(th, &s, &c);
    p[d]      = __float2bfloat16(x1 * c + x2 * s);
    p[d + 64] = __float2bfloat16(-x1 * s + x2 * c);
}

// ---------------- Flash attention v7: double-buffered K/V, 1 barrier per chunk ----------------
// Static-max softmax (RMS-normed q,k => |score*scale| <= 11.32; exp(s-16) exact).
// Block = 512 thr: group g = waves 0-3 / 4-7; both groups cover the same 128 q-rows
// (wave wl -> rows qb*128 + wl*32, two 16-row tiles) but disjoint 32-key chunks
// (abs chunk 2c+g). Partial (O, l) add linearly (static max) -> fp32 LDS merge.
// Pass pairing (p, 15-p) => uniform 34 group-chunks/block.
// One __syncthreads per chunk: iteration c writes prefetched chunk c+1 into buf^1,
// issues the global prefetch of c+2, computes chunk c from buf, then barriers.
// QK^T swapped (mfma(kf,qf)): lane holds S[k][q=lr]; PV A-fragment built in-register
// with v_cvt_pk_bf16_f32 (no LDS round-trip for P); V k-order permuted at load.
__global__ __launch_bounds__(512, 2) void attn_k(const bf16* __restrict__ Q, const bf16* __restrict__ K,
                                                 const bf16* __restrict__ VT, bf16* __restrict__ Y)
{
    const int lane = threadIdx.x & 63;
    const int w = threadIdx.x >> 6;          // 0..7
    const int g = w >> 2, wl = w & 3;
    const int p = blockIdx.x, h = blockIdx.y, b = blockIdx.z;
    const int lr = lane & 15, quad = lane >> 4, lk = quad * 8;
    const bf16* Qb = Q  + (size_t)(b * NH  + h)        * T_SEQ * DH;
    const bf16* Kb = K  + (size_t)(b * NKV + (h >> 2)) * T_SEQ * DH;
    const bf16* Vb = VT + (size_t)(b * NKV + (h >> 2)) * DH * T_SEQ;

    __shared__ __align__(16) union ShmU {
        struct { bf16 SK[2][2][32 * 128]; bf16 SV[2][2][128 * 32]; } s;   // 64 KiB (dbuf)
        ffrag MRG[9 * 4 * 64];               // 36864 B merge area (aliases SK/SV)
    } shm;

    // staging coords: K chunk 32(keys)x128, V chunk 128(d)x32(keys), per group
    const int k_r0 = wl * 8 + (lane >> 4);   // + j*4
    const int k_ch = lane & 15;
    const int v_r0 = wl * 32 + (lane >> 2);  // + j*16
    const int v_ch = lane & 3;
    const int vsw = (lr + (lr >> 2)) & 3;    // SV read swizzle (row = dt*16+lr)
    const float scale = 0.08838834764831845f;            // 1/sqrt(128)

    // k-permuted V load: slot v_ch holds k = {4*v_ch..+3, 16+4*v_ch..+3}
    auto load_v_perm = [&](const bf16* rp) {
        union { bhalf h[2]; bfrag f; } u;
        u.h[0] = *(const bhalf*)(rp + v_ch * 4);
        u.h[1] = *(const bhalf*)(rp + 16 + v_ch * 4);
        return u.f;
    };

    for (int pass = 0; pass < 2; ++pass) {
        const int qb = pass ? (15 - p) : p;
        const int nc = 2 * (qb + 1);         // 32-key chunks for THIS group
        const int q0 = qb * 128 + wl * 32;

        bfrag qf[2][4];
        #pragma unroll
        for (int t = 0; t < 2; ++t)
            #pragma unroll
            for (int dc = 0; dc < 4; ++dc)
                qf[t][dc] = *(const bfrag*)(Qb + (size_t)(q0 + t * 16 + lr) * DH + dc * 32 + lk);

        float lp[2] = {};
        ffrag o[2][8] = {};

        bfrag kr[2], vr[2];
        // prologue: load chunk 0, write it to buf 0, then prefetch chunk 1
        {
            const int b0 = g * 32;
            #pragma unroll
            for (int j = 0; j < 2; ++j) {
                kr[j] = *(const bfrag*)(Kb + (size_t)(b0 + k_r0 + j * 4) * DH + k_ch * 8);
                vr[j] = load_v_perm(Vb + (size_t)(v_r0 + j * 16) * T_SEQ + b0);
            }
            #pragma unroll
            for (int j = 0; j < 2; ++j) {
                int krow = k_r0 + j * 4;
                *(bfrag*)&shm.s.SK[g][0][krow * 128 + ((k_ch ^ (krow & 15))) * 8] = kr[j];
                int vrow = v_r0 + j * 16;
                *(bfrag*)&shm.s.SV[g][0][vrow * 32 + ((v_ch ^ ((vrow + (vrow >> 2)) & 3))) * 8] = vr[j];
            }
            if (nc > 1) {
                const int nb = 64 + g * 32;
                #pragma unroll
                for (int j = 0; j < 2; ++j) {
                    kr[j] = *(const bfrag*)(Kb + (size_t)(nb + k_r0 + j * 4) * DH + k_ch * 8);
                    vr[j] = load_v_perm(Vb + (size_t)(v_r0 + j * 16) * T_SEQ + nb);
                }
            }
        }
        __syncthreads();                     // buf 0 visible (also isolates prior MRG use)

        for (int c = 0; c < nc; ++c) {
            const int cur = c & 1, nxt = cur ^ 1;
            const int base = c * 64 + g * 32;
            const bf16* SKc = shm.s.SK[g][cur];
            const bf16* SVc = shm.s.SV[g][cur];

            if (c + 1 < nc) {                // write prefetched chunk c+1 into buf^1
                #pragma unroll
                for (int j = 0; j < 2; ++j) {
                    int krow = k_r0 + j * 4;
                    *(bfrag*)&shm.s.SK[g][nxt][krow * 128 + ((k_ch ^ (krow & 15))) * 8] = kr[j];
                    int vrow = v_r0 + j * 16;
                    *(bfrag*)&shm.s.SV[g][nxt][vrow * 32 + ((v_ch ^ ((vrow + (vrow >> 2)) & 3))) * 8] = vr[j];
                }
                if (c + 2 < nc) {            // prefetch chunk c+2 (hides under compute)
                    const int nb = (c + 2) * 64 + g * 32;
                    #pragma unroll
                    for (int j = 0; j < 2; ++j) {
                        kr[j] = *(const bfrag*)(Kb + (size_t)(nb + k_r0 + j * 4) * DH + k_ch * 8);
                        vr[j] = load_v_perm(Vb + (size_t)(v_r0 + j * 16) * T_SEQ + nb);
                    }
                }
            }

            // QK^T (swapped): s2[t][kt][i] = S[k = base + kt*16 + quad*4 + i][q = q0 + t*16 + lr]
            ffrag s2[2][2] = {};
            #pragma unroll
            for (int kt = 0; kt < 2; ++kt)
                #pragma unroll
                for (int dc = 0; dc < 4; ++dc) {
                    bfrag kf = *(const bfrag*)&SKc[(kt * 16 + lr) * 128 + (((dc << 2) | quad) ^ lr) * 8];
                    s2[0][kt] = __builtin_amdgcn_mfma_f32_16x16x32_bf16(kf, qf[0][dc], s2[0][kt], 0, 0, 0);
                    s2[1][kt] = __builtin_amdgcn_mfma_f32_16x16x32_bf16(kf, qf[1][dc], s2[1][kt], 0, 0, 0);
                }

            // softmax numerator (static max); P built in-register (no LDS round-trip)
            const bool maskc = (c >= 2 * qb);
            bfrag pf[2];
            #pragma unroll
            for (int t = 0; t < 2; ++t) {
                const int qa = q0 + t * 16 + lr;
                float ev[2][4];
                #pragma unroll
                for (int kt = 0; kt < 2; ++kt)
                    #pragma unroll
                    for (int i = 0; i < 4; ++i) {
                        const int ka = base + kt * 16 + quad * 4 + i;
                        float e = (!maskc || ka <= qa) ? __expf(fmaf(s2[t][kt][i], scale, -16.0f)) : 0.0f;
                        lp[t] += e;
                        ev[kt][i] = e;
                    }
                union { unsigned u[4]; bfrag f; } pu;
                pu.u[0] = cvt_pk_bf16(ev[0][0], ev[0][1]);
                pu.u[1] = cvt_pk_bf16(ev[0][2], ev[0][3]);
                pu.u[2] = cvt_pk_bf16(ev[1][0], ev[1][1]);
                pu.u[3] = cvt_pk_bf16(ev[1][2], ev[1][3]);
                pf[t] = pu.f;
            }

            // P.V: pf is the A-fragment directly (k-order matches V's slot permutation)
            #pragma unroll
            for (int dt = 0; dt < 8; ++dt) {
                bfrag vf = *(const bfrag*)&SVc[(dt * 16 + lr) * 32 + ((quad ^ vsw)) * 8];
                o[0][dt] = __builtin_amdgcn_mfma_f32_16x16x32_bf16(pf[0], vf, o[0][dt], 0, 0, 0);
                o[1][dt] = __builtin_amdgcn_mfma_f32_16x16x32_bf16(pf[1], vf, o[1][dt], 0, 0, 0);
            }

            __syncthreads();                 // single barrier: cur fully read, nxt fully written
        }

        // merge groups (fp32, two rounds to fit LDS) + epilogue by group 0
        __syncthreads();
        #pragma unroll
        for (int t = 0; t < 2; ++t) {
            if (g == 1) {
                #pragma unroll
                for (int d = 0; d < 8; ++d) shm.MRG[(d * 4 + wl) * 64 + lane] = o[t][d];
                ffrag l4 = {lp[t], 0.0f, 0.0f, 0.0f};
                shm.MRG[(8 * 4 + wl) * 64 + lane] = l4;
            }
            __syncthreads();
            if (g == 0) {
                #pragma unroll
                for (int d = 0; d < 8; ++d) o[t][d] += shm.MRG[(d * 4 + wl) * 64 + lane];
                float lsum = lp[t] + shm.MRG[(8 * 4 + wl) * 64 + lane][0];
                lsum += __shfl_xor(lsum, 16);
                lsum += __shfl_xor(lsum, 32);         // total l for q = lr, all quads
                float inv[4];
                #pragma unroll
                for (int i = 0; i < 4; ++i)
                    inv[i] = 1.0f / __shfl(lsum, quad * 4 + i);   // l for q = quad*4+i
                #pragma unroll
                for (int dt = 0; dt < 8; ++dt)
                    #pragma unroll
                    for (int i = 0; i < 4; ++i) {
                        int row = q0 + t * 16 + quad * 4 + i;
                        Y[((size_t)(b * T_SEQ) + row) * CDIM + h * DH + dt * 16 + lr] =
                            __float2bfloat16(o[t][dt][i] * inv[i]);
                    }
            }
            __syncthreads();                 // protect MRG before next round / next pass
        }
    }
}

extern "C" void kernel_launch(void* const* d_in, const int* in_sizes, int n_in,
                              void* d_out, int out_size, void* d_ws, size_t ws_size,
                              hipStream_t stream) {
    const float* x     = (const float*)d_in[0];
    const float* Wq    = (const float*)d_in[1];
    const float* Wkv   = (const float*)d_in[2];
    const float* Wproj = (const float*)d_in[3];
    float* out = (float*)d_out;

    char* ws = (char*)d_ws;
    size_t off = 0;
    auto alloc = [&](size_t bytes) { void* p = ws + off; off += (bytes + 255) & ~255ULL; return p; };
    bf16* xb   = (bf16*)alloc((size_t)BATCH * T_SEQ * CDIM * 2);
    bf16* wqb  = (bf16*)alloc((size_t)CDIM * CDIM * 2);
    bf16* wkvb = (bf16*)alloc((size_t)2 * NKV * DH * CDIM * 2);
    bf16* wpb  = (bf16*)alloc((size_t)CDIM * CDIM * 2);
    bf16* qb   = (bf16*)alloc((size_t)BATCH * NH * T_SEQ * DH * 2);
    bf16* kb   = (bf16*)alloc((size_t)BATCH * NKV * T_SEQ * DH * 2);
    bf16* vtb  = (bf16*)alloc((size_t)BATCH * NKV * DH * T_SEQ * 2);
    bf16* y1   = (bf16*)alloc((size_t)BATCH * T_SEQ * CDIM * 2);

    const int total4 = N4_X + N4_WQ + N4_WKV + N4_WP;
    cast_all<<<(total4 + 255) / 256, 256, 0, stream>>>(x, Wq, Wkv, Wproj, xb, wqb, wkvb, wpb);

    gemm_qkv<<<dim3(32, 24), 256, 0, stream>>>(xb, wqb, wkvb, qb, kb, vtb);
    normrope_k<<<(QROWS + KROWS) / 4, 256, 0, stream>>>(qb, kb);
    attn_k<<<dim3(8, NH, BATCH), 512, 0, stream>>>(qb, kb, vtb, y1);
    gemm_proj<<<dim3(32, 32), 256, 0, stream>>>(y1, wpb, out);
}